// Round 1
// baseline (113.797 us; speedup 1.0000x reference)
//
#include <hip/hip_runtime.h>

// MSDeformAttn sampling-weight scatter (RankDetr), bug-compatible with the
// reference's axis-mislabeled reshape: output column q' = m/48, m=(l*8+h)*300+q.
//
// Static shapes from setup_inputs():
//   N=1, L=6, Q=300, H=8, Lv=4, P=4
//   spatial_shapes = (100,167),(50,84),(25,42),(13,21); S = 22223
//   level_start    = 0, 16700, 20900, 21950
// Output (N, S, Q) fp32, flat index s*Q + q'.

constexpr int NL  = 6;
constexpr int NQ  = 300;
constexpr int NH  = 8;
constexpr int NLV = 4;
constexpr int NP  = 4;
constexpr int TOT = NL * NQ * NH * NLV * NP;   // 230400 samples
constexpr int S_TOT = 22223;

__global__ __launch_bounds__(256)
void msda_scatter(const float2* __restrict__ loc,   // (TOT, 2) = (x=col frac, y=row frac)
                  const float*  __restrict__ aw,    // (TOT,)
                  float*        __restrict__ out) { // (S_TOT, NQ)
    const int t = blockIdx.x * 256 + threadIdx.x;
    if (t >= TOT) return;

    // decode t = (((l*NQ + q)*NH + h)*NLV + lv)*NP + p   (attention_weights layout)
    int r  = t / NP;           // p unused beyond indexing
    const int lv = r % NLV;  r /= NLV;
    const int h  = r % NH;   r /= NH;
    const int q  = r % NQ;
    const int l  = r / NQ;

    // level constants (static)
    const int Wlv[NLV]  = {167, 84, 42, 21};
    const int Hlv[NLV]  = {100, 50, 25, 13};
    const int lsi[NLV]  = {0, 16700, 20900, 21950};
    const int W = Wlv[lv], Hh = Hlv[lv], base = lsi[lv];

    const float2 xy = loc[t];
    const float  w  = aw[t];

    const float cf = xy.x * (float)W;    // col coordinate in [0, W)
    const float rf = xy.y * (float)Hh;   // row coordinate in [0, H)
    const float cfl = floorf(cf), rfl = floorf(rf);
    const float fc = cf - cfl, fr = rf - rfl;
    const int c0 = (int)cfl, r0 = (int)rfl;

    // bug-compatible output column: m = (l*H + h)*Q + q, q' = m / (L*H)
    const int m    = (l * NH + h) * NQ + q;
    const int qout = m / (NL * NH);      // m / 48

    const float wll = w * (1.0f - fc) * (1.0f - fr);  // (c0,   r0  )
    const float wlh = w * (1.0f - fc) * fr;           // (c0,   r0+1)
    const float whl = w * fc * (1.0f - fr);           // (c0+1, r0  )
    const float whh = w * fc * fr;                    // (c0+1, r0+1)

    const int c1 = c0 + 1, r1 = r0 + 1;
    const bool cv0 = (c0 >= 0) & (c0 < W);
    const bool cv1 = (c1 >= 0) & (c1 < W);
    const bool rv0 = (r0 >= 0) & (r0 < Hh);
    const bool rv1 = (r1 >= 0) & (r1 < Hh);

    if (cv0 & rv0) atomicAdd(&out[(base + r0 * W + c0) * NQ + qout], wll);
    if (cv0 & rv1) atomicAdd(&out[(base + r1 * W + c0) * NQ + qout], wlh);
    if (cv1 & rv0) atomicAdd(&out[(base + r0 * W + c1) * NQ + qout], whl);
    if (cv1 & rv1) atomicAdd(&out[(base + r1 * W + c1) * NQ + qout], whh);
}

extern "C" void kernel_launch(void* const* d_in, const int* in_sizes, int n_in,
                              void* d_out, int out_size, void* d_ws, size_t ws_size,
                              hipStream_t stream) {
    const float2* loc = (const float2*)d_in[0];   // sampling_locations (fp32, 2*TOT)
    const float*  aw  = (const float*)d_in[1];    // attention_weights  (fp32, TOT)
    float* out = (float*)d_out;                   // (S_TOT * NQ) fp32

    // d_out is poisoned to 0xAA before every timed launch — zero it first.
    hipMemsetAsync(out, 0, (size_t)S_TOT * NQ * sizeof(float), stream);

    constexpr int BLK = 256;
    msda_scatter<<<(TOT + BLK - 1) / BLK, BLK, 0, stream>>>(loc, aw, out);
}

// Round 2
// 101.291 us; speedup vs baseline: 1.1235x; 1.1235x over previous
//
#include <hip/hip_runtime.h>

// MSDeformAttn sampling-weight scatter (RankDetr), bug-compatible with the
// reference's axis-mislabeled reshape: output column q' = m/48, m=(l*8+h)*300+q.
//
// Structure: gather-style privatization. Output (S=22223, Q=300) is tiled as
// (level-aligned row tiles) x (32-wide q' groups). One block per tile:
//   zero LDS tile -> scan the q-group's samples for this level, filter by
//   tile row range, LDS atomicAdd 4 bilinear corners -> coalesced float4
//   write-out. Every output cell is written exactly once => no memset needed.
//
// Static shapes: N=1, L=6, Q=300, H=8, Lv=4, P=4; TOT=230400 samples.
// spatial: (100,167),(50,84),(25,42),(13,21); lsi = 0,16700,20900,21950; S=22223.

constexpr int NQ   = 300;
constexpr int QW   = 32;                 // q'-group width
constexpr int NG   = 10;                 // ceil(300/32)
constexpr int NTILES = 47;               // 34 (L0,R=3) + 9 (L1,R=6) + 3 (L2,R=12) + 1 (L3)
constexpr int MAXC = 504;                // max cells per tile (L1/L2: 6*84 = 12*42 = 504)
constexpr int BLK  = 512;

__global__ __launch_bounds__(BLK)
void msda_tiled(const float2* __restrict__ loc,   // (TOT,2) = (x=col frac, y=row frac)
                const float*  __restrict__ aw,    // (TOT,)
                float*        __restrict__ out) { // (S, NQ)
    __shared__ float sm[MAXC * QW];               // 64,512 B

    const int b  = blockIdx.x;
    const int g  = b / NTILES;                    // q'-group 0..9
    const int tb = b % NTILES;                    // s-tile id

    int lv, r0t, nr;
    if (tb < 34)      { lv = 0; r0t = 3  * tb;        nr = min(3,  100 - r0t); }
    else if (tb < 43) { lv = 1; r0t = 6  * (tb - 34); nr = min(6,  50  - r0t); }
    else if (tb < 46) { lv = 2; r0t = 12 * (tb - 43); nr = min(12, 25  - r0t); }
    else              { lv = 3; r0t = 0;              nr = 13; }

    const int Wlv_[4] = {167, 84, 42, 21};
    const int Hlv_[4] = {100, 50, 25, 13};
    const int lsi_[4] = {0, 16700, 20900, 21950};
    const int W    = Wlv_[lv];
    const int base = lsi_[lv];
    const int g0   = g * QW;
    const int qw   = min(QW, NQ - g0);            // 32, or 12 for the last group
    const int cells = nr * W;
    const int tid  = threadIdx.x;

    for (int i = tid; i < cells * QW; i += BLK) sm[i] = 0.0f;
    __syncthreads();

    // samples of this (q-group, level): m in [48*g0, 48*g0 + 48*qw), p in [0,4)
    const int nm  = 48 * qw;
    const int rlo = r0t, rhi = r0t + nr;          // rhi <= H, rlo >= 0
    const float fW = (float)W, fH = (float)Hlv_[lv];

    for (int i = tid; i < nm * 4; i += BLK) {
        const int mi = i >> 2, p = i & 3;
        const int m  = 48 * g0 + mi;
        const int ql = mi / 48;                   // local q' index in [0, qw)
        const int l  = m / 2400;
        const int rem = m - l * 2400;
        const int h  = rem / 300;
        const int q  = rem - h * 300;
        const int t  = (((l * 300 + q) * 8 + h) * 4 + lv) * 4 + p;

        const float2 xy = loc[t];
        const float  w  = aw[t];

        const float cf  = xy.x * fW;
        const float rf  = xy.y * fH;
        const float cfl = floorf(cf), rfl = floorf(rf);
        const float fc  = cf - cfl, fr = rf - rfl;
        const int c0 = (int)cfl, rr = (int)rfl;
        const int c1 = c0 + 1, r1 = rr + 1;

        const bool cv0 = (unsigned)c0 < (unsigned)W;   // 0 <= c0 < W
        const bool cv1 = (unsigned)c1 < (unsigned)W;
        const bool rv0 = (rr >= rlo) & (rr < rhi);     // in-tile (implies 0<=r<H)
        const bool rv1 = (r1 >= rlo) & (r1 < rhi);

        const float omfc = 1.0f - fc, omfr = 1.0f - fr;
        if (rv0) {
            const int ro = (rr - rlo) * W;
            if (cv0) atomicAdd(&sm[(ro + c0) * QW + ql], w * omfc * omfr);
            if (cv1) atomicAdd(&sm[(ro + c1) * QW + ql], w * fc   * omfr);
        }
        if (rv1) {
            const int ro = (r1 - rlo) * W;
            if (cv0) atomicAdd(&sm[(ro + c0) * QW + ql], w * omfc * fr);
            if (cv1) atomicAdd(&sm[(ro + c1) * QW + ql], w * fc   * fr);
        }
    }
    __syncthreads();

    // write-out: tile covers s in [base + r0t*W, base + r0t*W + cells),
    // q' in [g0, g0+qw). float4-aligned since 300%4==0 and g0%4==0.
    const int s0  = base + r0t * W;
    const int nq4 = qw >> 2;                      // 8 or 3
    for (int i = tid; i < cells * nq4; i += BLK) {
        const int cell = i / nq4;
        const int v    = i - cell * nq4;
        const float4 val = *(const float4*)&sm[cell * QW + v * 4];
        *(float4*)&out[(s0 + cell) * NQ + g0 + v * 4] = val;
    }
}

extern "C" void kernel_launch(void* const* d_in, const int* in_sizes, int n_in,
                              void* d_out, int out_size, void* d_ws, size_t ws_size,
                              hipStream_t stream) {
    const float2* loc = (const float2*)d_in[0];   // sampling_locations (fp32)
    const float*  aw  = (const float*)d_in[1];    // attention_weights  (fp32)
    float* out = (float*)d_out;

    msda_tiled<<<NG * NTILES, BLK, 0, stream>>>(loc, aw, out);
}

// Round 3
// 86.463 us; speedup vs baseline: 1.3161x; 1.1715x over previous
//
#include <hip/hip_runtime.h>

// MSDeformAttn sampling-weight scatter (RankDetr), bug-compatible with the
// reference's axis-mislabeled reshape: output column q' = m/48, m=(l*8+h)*300+q.
//
// Gather-style privatization. Output (S=22223, Q=300) tiled as (level-aligned
// row tiles) x (16-wide q' groups). One block per tile: zero LDS -> scan the
// q-group's samples for this level, filter by tile rows, LDS-atomic the 4
// bilinear corners -> coalesced float4 write-out. Output written exactly once.
//
// LDS layout is ql-MAJOR: sm[ql*MAXC + cell]. Within a wave all lanes share
// ql but have random cells -> banks spread uniformly. (The previous QW-minor
// layout put all 64 lanes of every atomic on ONE bank: 64-way conflict.)
//
// Static shapes: N=1, L=6, Q=300, H=8, Lv=4, P=4; TOT=230400 samples.
// spatial: (100,167),(50,84),(25,42),(13,21); lsi = 0,16700,20900,21950.

constexpr int NQ   = 300;
constexpr int QW   = 16;                 // q'-group width
constexpr int NG   = 19;                 // ceil(300/16)
constexpr int NTILES = 25;               // 17 (L0,R=6) + 5 (L1,R=12) + 2 (L2,R=24) + 1 (L3)
constexpr int MAXC = 1008;               // max cells per tile (6*167=1002, 12*84=1008, 24*42=1008)
constexpr int BLK  = 512;

__global__ __launch_bounds__(BLK)
void msda_tiled(const float2* __restrict__ loc,   // (TOT,2) = (x=col frac, y=row frac)
                const float*  __restrict__ aw,    // (TOT,)
                float*        __restrict__ out) { // (S, NQ)
    __shared__ float sm[QW * MAXC];               // 64,512 B, ql-major

    const int b  = blockIdx.x;
    const int g  = b / NTILES;                    // q'-group 0..18
    const int tb = b % NTILES;                    // s-tile id

    int lv, r0t, nr;
    if (tb < 17)      { lv = 0; r0t = 6  * tb;        nr = min(6,  100 - r0t); }
    else if (tb < 22) { lv = 1; r0t = 12 * (tb - 17); nr = min(12, 50  - r0t); }
    else if (tb < 24) { lv = 2; r0t = 24 * (tb - 22); nr = min(24, 25  - r0t); }
    else              { lv = 3; r0t = 0;              nr = 13; }

    const int Wlv_[4] = {167, 84, 42, 21};
    const int Hlv_[4] = {100, 50, 25, 13};
    const int lsi_[4] = {0, 16700, 20900, 21950};
    const int W    = Wlv_[lv];
    const int base = lsi_[lv];
    const int g0   = g * QW;
    const int qw   = min(QW, NQ - g0);            // 16, or 12 for the last group
    const int cells = nr * W;
    const int tid  = threadIdx.x;

    for (int i = tid; i < QW * MAXC; i += BLK) sm[i] = 0.0f;
    __syncthreads();

    // samples of this (q-group, level): m in [48*g0, 48*g0 + 48*qw), p in [0,4)
    const int nm4 = 48 * qw * 4;                  // 3072 (or 2304 last group)
    const int rlo = r0t, rhi = r0t + nr;
    const float fW = (float)W, fH = (float)Hlv_[lv];

    for (int i = tid; i < nm4; i += BLK) {
        const int mi = i >> 2, p = i & 3;
        const int m  = 48 * g0 + mi;
        const int ql = mi / 48;                   // local q' index in [0, qw)
        const int l  = m / 2400;
        const int rem = m - l * 2400;
        const int h  = rem / 300;
        const int q  = rem - h * 300;
        const int t  = (((l * 300 + q) * 8 + h) * 4 + lv) * 4 + p;

        const float2 xy = loc[t];
        const float  w  = aw[t];

        const float cf  = xy.x * fW;
        const float rf  = xy.y * fH;
        const float cfl = floorf(cf), rfl = floorf(rf);
        const float fc  = cf - cfl, fr = rf - rfl;
        const int c0 = (int)cfl, rr = (int)rfl;
        const int c1 = c0 + 1, r1 = rr + 1;

        const bool cv0 = (unsigned)c0 < (unsigned)W;   // 0 <= c0 < W
        const bool cv1 = (unsigned)c1 < (unsigned)W;
        const bool rv0 = (rr >= rlo) & (rr < rhi);     // in-tile (implies 0<=r<H)
        const bool rv1 = (r1 >= rlo) & (r1 < rhi);

        const float omfc = 1.0f - fc, omfr = 1.0f - fr;
        float* smq = &sm[ql * MAXC];
        if (rv0) {
            const int ro = (rr - rlo) * W;
            if (cv0) atomicAdd(&smq[ro + c0], w * omfc * omfr);
            if (cv1) atomicAdd(&smq[ro + c1], w * fc   * omfr);
        }
        if (rv1) {
            const int ro = (r1 - rlo) * W;
            if (cv0) atomicAdd(&smq[ro + c0], w * omfc * fr);
            if (cv1) atomicAdd(&smq[ro + c1], w * fc   * fr);
        }
    }
    __syncthreads();

    // write-out: s in [base + r0t*W, +cells), q' in [g0, g0+qw).
    // float4 per (cell, v): gather 4 strided LDS scalars, one 16B global store.
    const int s0  = base + r0t * W;
    const int nq4 = qw >> 2;                      // 4 or 3
    for (int i = tid; i < cells * nq4; i += BLK) {
        const int cell = i / nq4;
        const int v    = i - cell * nq4;
        float4 val;
        val.x = sm[(v * 4 + 0) * MAXC + cell];
        val.y = sm[(v * 4 + 1) * MAXC + cell];
        val.z = sm[(v * 4 + 2) * MAXC + cell];
        val.w = sm[(v * 4 + 3) * MAXC + cell];
        *(float4*)&out[(s0 + cell) * NQ + g0 + v * 4] = val;
    }
}

extern "C" void kernel_launch(void* const* d_in, const int* in_sizes, int n_in,
                              void* d_out, int out_size, void* d_ws, size_t ws_size,
                              hipStream_t stream) {
    const float2* loc = (const float2*)d_in[0];   // sampling_locations (fp32)
    const float*  aw  = (const float*)d_in[1];    // attention_weights  (fp32)
    float* out = (float*)d_out;

    msda_tiled<<<NG * NTILES, BLK, 0, stream>>>(loc, aw, out);
}

// Round 4
// 82.721 us; speedup vs baseline: 1.3757x; 1.0452x over previous
//
#include <hip/hip_runtime.h>

// MSDeformAttn sampling-weight scatter (RankDetr), bug-compatible with the
// reference's axis-mislabeled reshape: output column q' = m/48, m=(l*8+h)*300+q.
//
// Gather-style privatization. Output (S=22223, Q=300) tiled as (level-aligned
// row tiles) x (8-wide q' groups). One block per tile: zero LDS (float4) ->
// scan the q-group's samples for this level, filter by tile rows, LDS-atomic
// the 4 bilinear corners -> coalesced write-out. Output written exactly once,
// no memset needed.
//
// LDS is ql-major sm[ql*MAXC + cell]: atomic banks = cell%32 (random, ~2-way
// = free); write-out 2 lanes/bank = free. QW=8 (vs 16) doubles rows/tile ->
// 14 tiles (L2/L3 whole-level), cutting redundant sample scans ~2x.
//
// Static shapes: N=1, L=6, Q=300, H=8, Lv=4, P=4; TOT=230400 samples.
// spatial: (100,167),(50,84),(25,42),(13,21); lsi = 0,16700,20900,21950.

constexpr int NQ   = 300;
constexpr int QW   = 8;                  // q'-group width
constexpr int NG   = 38;                 // ceil(300/8)
constexpr int NTILES = 14;               // 9 (L0,R=12) + 3 (L1,R=24) + 1 (L2) + 1 (L3)
constexpr int MAXC = 2016;               // max cells: L0 12*167=2004, L1 24*84=2016
constexpr int BLK  = 512;

__global__ __launch_bounds__(BLK)
void msda_tiled(const float2* __restrict__ loc,   // (TOT,2) = (x=col frac, y=row frac)
                const float*  __restrict__ aw,    // (TOT,)
                float*        __restrict__ out) { // (S, NQ)
    __shared__ float sm[QW * MAXC];               // 64,512 B, ql-major

    const int b  = blockIdx.x;
    const int g  = b / NTILES;                    // q'-group 0..37
    const int tb = b % NTILES;                    // s-tile id

    int lv, r0t, nr;
    if (tb < 9)       { lv = 0; r0t = 12 * tb;        nr = min(12, 100 - r0t); }
    else if (tb < 12) { lv = 1; r0t = 24 * (tb - 9);  nr = min(24, 50  - r0t); }
    else if (tb < 13) { lv = 2; r0t = 0;              nr = 25; }
    else              { lv = 3; r0t = 0;              nr = 13; }

    const int Wlv_[4] = {167, 84, 42, 21};
    const int Hlv_[4] = {100, 50, 25, 13};
    const int lsi_[4] = {0, 16700, 20900, 21950};
    const int W    = Wlv_[lv];
    const int base = lsi_[lv];
    const int g0   = g * QW;
    const int qw   = min(QW, NQ - g0);            // 8, or 4 for the last group
    const int cells = nr * W;
    const int tid  = threadIdx.x;

    // zero LDS with ds_write_b128
    float4* sm4 = (float4*)sm;
    for (int i = tid; i < QW * MAXC / 4; i += BLK) sm4[i] = make_float4(0.f, 0.f, 0.f, 0.f);
    __syncthreads();

    // samples of this (q-group, level): m in [48*g0, 48*g0 + 48*qw), p in [0,4)
    const int nm4 = 48 * qw * 4;                  // 1536 (or 768 last group)
    const int rlo = r0t, rhi = r0t + nr;
    const float fW = (float)W, fH = (float)Hlv_[lv];
    const int m0 = 48 * g0;

    for (int i = tid; i < nm4; i += BLK) {
        const int mi = i >> 2, p = i & 3;
        const int m  = m0 + mi;
        const int ql = mi / 48;                   // local q' index in [0, qw)
        const int l  = m / 2400;
        const int rem = m - l * 2400;
        const int h  = rem / 300;
        const int q  = rem - h * 300;
        const int t  = (((l * 300 + q) * 8 + h) * 4 + lv) * 4 + p;

        const float2 xy = loc[t];
        const float  w  = aw[t];

        const float cf  = xy.x * fW;
        const float rf  = xy.y * fH;
        const float cfl = floorf(cf), rfl = floorf(rf);
        const float fc  = cf - cfl, fr = rf - rfl;
        const int c0 = (int)cfl, rr = (int)rfl;
        const int c1 = c0 + 1, r1 = rr + 1;

        const bool cv0 = (unsigned)c0 < (unsigned)W;   // 0 <= c0 < W
        const bool cv1 = (unsigned)c1 < (unsigned)W;
        const bool rv0 = (rr >= rlo) & (rr < rhi);     // in-tile (implies 0<=r<H)
        const bool rv1 = (r1 >= rlo) & (r1 < rhi);

        const float omfc = 1.0f - fc, omfr = 1.0f - fr;
        float* smq = &sm[ql * MAXC];
        if (rv0) {
            const int ro = (rr - rlo) * W;
            if (cv0) atomicAdd(&smq[ro + c0], w * omfc * omfr);
            if (cv1) atomicAdd(&smq[ro + c1], w * fc   * omfr);
        }
        if (rv1) {
            const int ro = (r1 - rlo) * W;
            if (cv0) atomicAdd(&smq[ro + c0], w * omfc * fr);
            if (cv1) atomicAdd(&smq[ro + c1], w * fc   * fr);
        }
    }
    __syncthreads();

    // write-out: s in [base + r0t*W, +cells), q' in [g0, g0+qw).
    // One float4 global store per (cell, v); LDS gathers are 2 lanes/bank (free).
    const int s0  = base + r0t * W;
    const int nq4 = qw >> 2;                      // 2 (or 1 last group)
    for (int i = tid; i < cells * nq4; i += BLK) {
        const int cell = i / nq4;
        const int v    = i - cell * nq4;
        float4 val;
        val.x = sm[(v * 4 + 0) * MAXC + cell];
        val.y = sm[(v * 4 + 1) * MAXC + cell];
        val.z = sm[(v * 4 + 2) * MAXC + cell];
        val.w = sm[(v * 4 + 3) * MAXC + cell];
        *(float4*)&out[(s0 + cell) * NQ + g0 + v * 4] = val;
    }
}

extern "C" void kernel_launch(void* const* d_in, const int* in_sizes, int n_in,
                              void* d_out, int out_size, void* d_ws, size_t ws_size,
                              hipStream_t stream) {
    const float2* loc = (const float2*)d_in[0];   // sampling_locations (fp32)
    const float*  aw  = (const float*)d_in[1];    // attention_weights  (fp32)
    float* out = (float*)d_out;

    msda_tiled<<<NG * NTILES, BLK, 0, stream>>>(loc, aw, out);
}